// Round 3
// baseline (68.594 us; speedup 1.0000x reference)
//
#include <hip/hip_runtime.h>
#include <hip/hip_bf16.h>
#include <math.h>

// Problem constants (from reference setup_inputs)
#define BB 16
#define QQ 1000
#define CC 91
#define TT 128

#define COST_CLASS 2.0f
#define COST_BBOX  5.0f
#define COST_GIOU  2.0f
#define ALPHA 0.25f
#define GAMMA 2.0f
#define EPS   1e-8f

// out[b,q,t] = COST_BBOX * L1(pbox[b,q], tbox[b,t])
//            + COST_CLASS * focal(sigmoid(logit[b,q,label[b,t]]))
//            + COST_GIOU * (-GIoU(xyxy(pbox), xyxy(tbox)))
//
// Thread mapping: flat idx = ((b*Q)+q)*T + t, t fastest -> coalesced stores,
// coalesced tgt loads (16B/lane), wave-uniform pred-box loads (broadcast).
__global__ __launch_bounds__(256) void matcher_kernel(
        const float* __restrict__ logits,   // [B,Q,C]
        const float* __restrict__ pboxes,   // [B,Q,4] cxcywh
        const int*   __restrict__ labels,   // [B,T]
        const float* __restrict__ tboxes,   // [B,T,4] cxcywh
        float* __restrict__ out)            // [B,Q,T]
{
    const int idx = blockIdx.x * 256 + threadIdx.x;   // exactly B*Q*T = 2,048,000
    const int t  = idx & (TT - 1);
    const int bq = idx >> 7;                          // TT == 128
    const int b  = bq / QQ;

    // ---- loads ----
    const float4 pb = *reinterpret_cast<const float4*>(pboxes + (size_t)bq * 4);
    const float4 tb = *reinterpret_cast<const float4*>(tboxes + ((size_t)b * TT + t) * 4);
    const int    lab = labels[b * TT + t];
    const float  logit = logits[((size_t)bq * CC) + lab];

    // ---- cost_class (focal) ----
    const float p = 1.0f / (1.0f + expf(-logit));
    const float neg_cost = (1.0f - ALPHA) * (p * p) * (-logf(1.0f - p + EPS));
    const float pos_cost = ALPHA * ((1.0f - p) * (1.0f - p)) * (-logf(p + EPS));
    const float cost_class = pos_cost - neg_cost;

    // ---- cost_bbox: L1 in cxcywh space ----
    const float cost_bbox = fabsf(pb.x - tb.x) + fabsf(pb.y - tb.y)
                          + fabsf(pb.z - tb.z) + fabsf(pb.w - tb.w);

    // ---- GIoU in xyxy space ----
    const float ax0 = pb.x - 0.5f * pb.z, ay0 = pb.y - 0.5f * pb.w;
    const float ax1 = pb.x + 0.5f * pb.z, ay1 = pb.y + 0.5f * pb.w;
    const float bx0 = tb.x - 0.5f * tb.z, by0 = tb.y - 0.5f * tb.w;
    const float bx1 = tb.x + 0.5f * tb.z, by1 = tb.y + 0.5f * tb.w;

    const float area_a = (ax1 - ax0) * (ay1 - ay0);
    const float area_b = (bx1 - bx0) * (by1 - by0);

    const float ltx = fmaxf(ax0, bx0), lty = fmaxf(ay0, by0);
    const float rbx = fminf(ax1, bx1), rby = fminf(ay1, by1);
    const float iw = fmaxf(rbx - ltx, 0.0f), ih = fmaxf(rby - lty, 0.0f);
    const float inter = iw * ih;
    const float uni = area_a + area_b - inter;
    const float iou = inter / uni;

    const float ex0 = fminf(ax0, bx0), ey0 = fminf(ay0, by0);
    const float ex1 = fmaxf(ax1, bx1), ey1 = fmaxf(ay1, by1);
    const float ew = fmaxf(ex1 - ex0, 0.0f), eh = fmaxf(ey1 - ey0, 0.0f);
    const float area_e = ew * eh;
    const float giou = iou - (area_e - uni) / area_e;
    const float cost_giou = -giou;

    out[idx] = COST_BBOX * cost_bbox + COST_CLASS * cost_class + COST_GIOU * cost_giou;
}

extern "C" void kernel_launch(void* const* d_in, const int* in_sizes, int n_in,
                              void* d_out, int out_size, void* d_ws, size_t ws_size,
                              hipStream_t stream) {
    const float* logits = (const float*)d_in[0];   // [16,1000,91] f32
    const float* pboxes = (const float*)d_in[1];   // [16,1000,4]  f32
    const int*   labels = (const int*)  d_in[2];   // [16,128]     i32
    const float* tboxes = (const float*)d_in[3];   // [16,128,4]   f32
    float* out = (float*)d_out;                    // [16,1000,128] f32

    const int total = BB * QQ * TT;                // 2,048,000
    const int blocks = (total + 255) / 256;        // 8000
    matcher_kernel<<<blocks, 256, 0, stream>>>(logits, pboxes, labels, tboxes, out);
}

// Round 4
// 67.433 us; speedup vs baseline: 1.0172x; 1.0172x over previous
//
#include <hip/hip_runtime.h>
#include <hip/hip_bf16.h>
#include <math.h>

// Problem constants (from reference setup_inputs)
#define BB 16
#define QQ 1000
#define CC 91
#define TT 128

#define COST_CLASS 2.0f
#define COST_BBOX  5.0f
#define COST_GIOU  2.0f
#define ALPHA 0.25f
#define GAMMA 2.0f
#define EPS   1e-8f

// out[b,q,t] = COST_BBOX * L1(pbox[b,q], tbox[b,t])
//            + COST_CLASS * focal(sigmoid(logit[b,q,label[b,t]]))
//            + COST_GIOU * (-GIoU(xyxy(pbox), xyxy(tbox)))
//
// 4 targets per thread: float4 stores (16B/lane), int4 label loads,
// wave-uniform pred-box loads. Hardware transcendentals (__expf/__logf,
// v_rcp_f32) — absmax threshold 0.415 vs observed 0.031 leaves ~13x margin.
__global__ __launch_bounds__(256) void matcher_kernel(
        const float* __restrict__ logits,   // [B,Q,C]
        const float* __restrict__ pboxes,   // [B,Q,4] cxcywh
        const int*   __restrict__ labels,   // [B,T]
        const float* __restrict__ tboxes,   // [B,T,4] cxcywh
        float* __restrict__ out)            // [B,Q,T]
{
    const int idx = blockIdx.x * 256 + threadIdx.x;   // B*Q*(T/4) = 512,000
    const int t4 = idx & 31;                          // t-group: 4*t4 .. 4*t4+3
    const int bq = idx >> 5;
    const int b  = bq / QQ;

    // ---- wave-uniform-ish loads ----
    const float4 pb = *reinterpret_cast<const float4*>(pboxes + (size_t)bq * 4);
    const int4 lab4 = *reinterpret_cast<const int4*>(labels + b * TT + t4 * 4);

    // pred box in xyxy (computed once for 4 targets)
    const float ax0 = pb.x - 0.5f * pb.z, ay0 = pb.y - 0.5f * pb.w;
    const float ax1 = pb.x + 0.5f * pb.z, ay1 = pb.y + 0.5f * pb.w;
    const float area_a = (ax1 - ax0) * (ay1 - ay0);

    const float* lrow = logits + (size_t)bq * CC;
    const float* trow = tboxes + ((size_t)b * TT + t4 * 4) * 4;

    float4 res;
    float* resp = &res.x;
    const int labs[4] = {lab4.x, lab4.y, lab4.z, lab4.w};

#pragma unroll
    for (int j = 0; j < 4; ++j) {
        const float4 tb = *reinterpret_cast<const float4*>(trow + j * 4);
        const float logit = lrow[labs[j]];

        // ---- cost_class (focal), hw transcendentals ----
        const float p = __builtin_amdgcn_rcpf(1.0f + __expf(-logit));
        const float omp = 1.0f - p;
        const float neg_cost = (1.0f - ALPHA) * (p * p) * (-__logf(omp + EPS));
        const float pos_cost = ALPHA * (omp * omp) * (-__logf(p + EPS));
        const float cost_class = pos_cost - neg_cost;

        // ---- cost_bbox: L1 in cxcywh space ----
        const float cost_bbox = fabsf(pb.x - tb.x) + fabsf(pb.y - tb.y)
                              + fabsf(pb.z - tb.z) + fabsf(pb.w - tb.w);

        // ---- GIoU in xyxy space ----
        const float bx0 = tb.x - 0.5f * tb.z, by0 = tb.y - 0.5f * tb.w;
        const float bx1 = tb.x + 0.5f * tb.z, by1 = tb.y + 0.5f * tb.w;
        const float area_b = (bx1 - bx0) * (by1 - by0);

        const float ltx = fmaxf(ax0, bx0), lty = fmaxf(ay0, by0);
        const float rbx = fminf(ax1, bx1), rby = fminf(ay1, by1);
        const float iw = fmaxf(rbx - ltx, 0.0f), ih = fmaxf(rby - lty, 0.0f);
        const float inter = iw * ih;
        const float uni = area_a + area_b - inter;
        const float iou = inter * __builtin_amdgcn_rcpf(uni);

        const float ex0 = fminf(ax0, bx0), ey0 = fminf(ay0, by0);
        const float ex1 = fmaxf(ax1, bx1), ey1 = fmaxf(ay1, by1);
        const float area_e = fmaxf(ex1 - ex0, 0.0f) * fmaxf(ey1 - ey0, 0.0f);
        const float giou = iou - (area_e - uni) * __builtin_amdgcn_rcpf(area_e);

        resp[j] = COST_BBOX * cost_bbox + COST_CLASS * cost_class
                + COST_GIOU * (-giou);
    }

    reinterpret_cast<float4*>(out)[idx] = res;
}

extern "C" void kernel_launch(void* const* d_in, const int* in_sizes, int n_in,
                              void* d_out, int out_size, void* d_ws, size_t ws_size,
                              hipStream_t stream) {
    const float* logits = (const float*)d_in[0];   // [16,1000,91] f32
    const float* pboxes = (const float*)d_in[1];   // [16,1000,4]  f32
    const int*   labels = (const int*)  d_in[2];   // [16,128]     i32
    const float* tboxes = (const float*)d_in[3];   // [16,128,4]   f32
    float* out = (float*)d_out;                    // [16,1000,128] f32

    const int total = BB * QQ * (TT / 4);          // 512,000 threads
    const int blocks = (total + 255) / 256;        // 2000
    matcher_kernel<<<blocks, 256, 0, stream>>>(logits, pboxes, labels, tboxes, out);
}